// Round 15
// baseline (114.401 us; speedup 1.0000x reference)
//
#include <hip/hip_runtime.h>
#include <hip/hip_bf16.h>
#include <math.h>

// DecoderActor: B=16384, N=20, DM=128.
// M*sqrt(dm) = x B x^T + alpha_n + beta_m + c, B = Wn^T(Wk^T Wq)Wn,
// alpha/beta/c derived from xg = max_n x[n,:].
// Round 15: r14 with (1) fB half-staged in LDS (rt 0-3; rt 4-7 from L1/L2)
// -> LDS 47.4->31.4 KB -> 4 blocks/CU, grid exactly 4/CU, zero tail;
// (2) xg reduce: fold rows 16-19 via -inf select before the 16-lane tree
// (-96 bpermutes/wave). All fragment layouts r2/r5/r6/r9-verified.
#define DM 128
#define NN 20
#define NB 16384

#define OFF_A      0
#define OFF_AT     16384
#define OFF_WA     32768
#define OFF_WAT    49152
#define OFF_AG     65536
#define OFF_BMAT   81920
#define OFF_S1T    98304
#define OFF_S2T    114688
#define OFF_C2T    131072
#define OFF_U0     147456
#define OFF_V0     147584
#define OFF_T0     147712
#define OFF_W1     147840
#define OFF_AT0    147968
#define OFF_A0     148096
#define OFF_B0     148224
#define OFF_C1     148352
#define OFF_C00    148480
#define OFF_CBASE  148481
// fp16 fragment arrays (packed by prep3; r2/r5/r6/r9-verified layout)
#define OFF_FRAGB  149504            // 16384 h16 : Bmat frags (dual B-op/A-op)
#define OFF_FRAGS  (149504 + 8192)   // 49152 h16 : matvec S frags (16x16x32 B-op)

#define INVS 0.08838834764831845f    // 1/sqrt(128)

typedef _Float16 h16;
typedef h16 half8 __attribute__((ext_vector_type(8)));
typedef h16 half4v __attribute__((ext_vector_type(4)));
typedef h16 half2v __attribute__((ext_vector_type(2)));
typedef float f32x4 __attribute__((ext_vector_type(4)));
typedef unsigned int uint4v __attribute__((ext_vector_type(4)));

#define MFMA16(a, b, c) __builtin_amdgcn_mfma_f32_16x16x32_f16((a), (b), (c), 0, 0, 0)

// r2/r5/r6-verified XOR swizzle (h16 units)
__device__ __forceinline__ int swz(int row, int col) {
    return (row * 128 + col) ^ ((row & 7) << 3);
}

// packed f16 max via pure clang builtin (v_pk_max_f16)
__device__ __forceinline__ unsigned pkmax(unsigned a, unsigned b) {
    const half2v r = __builtin_elementwise_max(__builtin_bit_cast(half2v, a),
                                               __builtin_bit_cast(half2v, b));
    return __builtin_bit_cast(unsigned, r);
}

__device__ __forceinline__ unsigned pk2(float a, float b) {
    const half2v p = { (h16)a, (h16)b };
    return __builtin_bit_cast(unsigned, p);
}

// fB fragment index for value Bmat[k][j]  (h16 units)
__device__ __forceinline__ int fb_idx(int k, int j) {
    return ((j >> 4) << 11) | ((k >> 5) << 9)
         | ((((k >> 3) & 3) * 16 + (j & 15)) << 3) | (k & 7);
}

// ---------- prep 1: A = Wk^T Wq (and A^T), u0, v0, t0, c00 ----------
__global__ void k_prep1(const float* __restrict__ Wk, const float* __restrict__ Wq,
                        const float* __restrict__ bk, const float* __restrict__ bq,
                        const float* __restrict__ bn, const float* __restrict__ bg,
                        float* __restrict__ ws) {
    const int bx = blockIdx.x, t = threadIdx.x;
    __shared__ float sbuf[128];
    if (bx < 128) {
        sbuf[t] = Wk[t * 128 + bx];
        __syncthreads();
        float a = 0.f;
        #pragma unroll 8
        for (int d = 0; d < 128; ++d) a += sbuf[d] * Wq[d * 128 + t];
        ws[OFF_A  + bx * 128 + t] = a;
        ws[OFF_AT + t * 128 + bx] = a;
    } else {
        float u = 0.f, v = 0.f;
        #pragma unroll 8
        for (int d = 0; d < 128; ++d) {
            u += Wk[d * 128 + t] * bq[d];
            v += Wq[d * 128 + t] * bk[d];
        }
        ws[OFF_U0 + t] = u;
        ws[OFF_V0 + t] = v;
        ws[OFF_T0 + t] = bn[t] + bg[t];
        sbuf[t] = bk[t] * bq[t];
        __syncthreads();
        for (int s = 64; s > 0; s >>= 1) { if (t < s) sbuf[t] += sbuf[t + s]; __syncthreads(); }
        if (t == 0) ws[OFF_C00] = sbuf[0];
    }
}

// ---------- prep 2: WA = Wn^T A, WAT = Wn^T A^T, AG = A Wg; w1, At0, c_base ----------
__global__ void k_prep2(const float* __restrict__ Wn, const float* __restrict__ Wg,
                        float* __restrict__ ws) {
    const int bx = blockIdx.x, t = threadIdx.x;
    __shared__ float s1[128], s2[128];
    if (bx < 128) {
        const int r = bx;
        s1[t] = Wn[t * 128 + r];
        s2[t] = ws[OFF_A + r * 128 + t];
        __syncthreads();
        float wa = 0.f, wat = 0.f, ag = 0.f;
        #pragma unroll 4
        for (int e = 0; e < 128; ++e) {
            wa  += s1[e] * ws[OFF_A  + e * 128 + t];
            wat += s1[e] * ws[OFF_AT + e * 128 + t];
            ag  += s2[e] * Wg[e * 128 + t];
        }
        ws[OFF_WA  + r * 128 + t] = wa;
        ws[OFF_WAT + r * 128 + t] = wat;
        ws[OFF_AG  + r * 128 + t] = ag;
    } else {
        const float t0t = ws[OFF_T0 + t], u0t = ws[OFF_U0 + t], v0t = ws[OFF_V0 + t];
        float w1 = 0.f, at0 = 0.f;
        #pragma unroll 8
        for (int e = 0; e < 128; ++e) {
            const float t0e = ws[OFF_T0 + e];
            w1  += (ws[OFF_A + t * 128 + e] + ws[OFF_AT + t * 128 + e]) * t0e;
            at0 +=  ws[OFF_A + t * 128 + e] * t0e;
        }
        w1 += u0t + v0t;
        ws[OFF_W1  + t] = w1;
        ws[OFF_AT0 + t] = at0;
        s1[t] = t0t * (at0 + u0t + v0t);
        __syncthreads();
        for (int s = 64; s > 0; s >>= 1) { if (t < s) s1[t] += s1[t + s]; __syncthreads(); }
        if (t == 0) ws[OFF_CBASE] = s1[0] + ws[OFF_C00];
    }
}

// ---------- prep 3 (+pack): Bmat/S1/S2/C2 -> fragment scatter; a0, b0, c1 ----------
__global__ void k_prep3(const float* __restrict__ Wn, const float* __restrict__ Wg,
                        float* __restrict__ ws) {
    const int bx = blockIdx.x, t = threadIdx.x;
    __shared__ float wa[128], wat[128], wgc[128];
    h16* fB = (h16*)(ws + OFF_FRAGB);
    h16* fS = (h16*)(ws + OFF_FRAGS);
    if (bx < 128) {
        const int r = bx;
        wa[t]  = ws[OFF_WA  + r * 128 + t];
        wat[t] = ws[OFF_WAT + r * 128 + t];
        wgc[t] = Wg[t * 128 + r];
        __syncthreads();
        float bm = 0.f, s1v = 0.f, s2v = 0.f, c2v = 0.f;
        #pragma unroll 4
        for (int f = 0; f < 128; ++f) {
            bm  += wa[f]  * Wn[f * 128 + t];             // Bmat[r][t]
            s1v += wa[f]  * Wg[f * 128 + t];             // S1[r][t] = Scat[t][r]
            s2v += wat[f] * Wg[f * 128 + t];             // S2[r][t] = Scat[t][r+128]
            c2v += wgc[f] * ws[OFF_AG + f * 128 + t];    // C2[r][t] = Scat[t][r+256]
        }
        fB[fb_idx(r, t)]       = (h16)bm;
        fS[fb_idx(t, r)]       = (h16)s1v;
        fS[fb_idx(t, r + 128)] = (h16)s2v;
        fS[fb_idx(t, r + 256)] = (h16)c2v;
    } else {
        float a0 = 0.f, b0 = 0.f, c1 = 0.f;
        #pragma unroll 8
        for (int f = 0; f < 128; ++f) {
            a0 += ws[OFF_WA  + t * 128 + f] * ws[OFF_T0 + f] + Wn[f * 128 + t] * ws[OFF_U0 + f];
            b0 += ws[OFF_WAT + t * 128 + f] * ws[OFF_T0 + f] + Wn[f * 128 + t] * ws[OFF_V0 + f];
            c1 += Wg[f * 128 + t] * ws[OFF_W1 + f];
        }
        ws[OFF_A0 + t] = a0;
        ws[OFF_B0 + t] = b0;
        ws[OFF_C1 + t] = c1;
    }
}

// ---------- fused main: 8 waves x 2 batches; fB half in LDS; x read once ----------
__global__ __launch_bounds__(512, 4) void k_fused(const float* __restrict__ x,
                                                  const float* __restrict__ ws,
                                                  float* __restrict__ out) {
    __shared__ __align__(16) h16 fBl[8192];            // 16 KB: fB rt 0-3
    __shared__ __align__(16) h16 xgl[16 * 128];        // 4 KB, swizzled
    __shared__ __align__(16) h16 avhL[16 * 2 * 128];   // 8 KB: avec|bvec (bias folded)
    __shared__ float abL[16][40];                      // 2.5 KB
    __shared__ float cpart[16][8];                     // 512 B
    __shared__ float cbs[16];                          // 64 B
    // total ~31.4 KB -> 4 blocks/CU (32 waves), grid = exactly 4/CU, no tail

    const int t = threadIdx.x, l = t & 63, w = t >> 6;
    const int lc = l & 15, lg = l >> 4;
    const int b0 = blockIdx.x * 16;
    const half8 h8z = {};

    // ---- stage fB lower half (rt 0-3) -> LDS ----
    {
        const float4* src = (const float4*)(ws + OFF_FRAGB);   // first 1024 float4
        float4* dst = (float4*)fBl;
        #pragma unroll
        for (int i = 0; i < 2; ++i) dst[t + 512 * i] = src[t + 512 * i];
    }

    // ---- load x fragments for this wave's 2 batches (verified layout) ----
    half8 xA0[4], xA1[4], xB0[4], xB1[4];
    {
        const float* xa = x + (size_t)(b0 + 2 * w) * 2560;
        const float* xb = x + (size_t)(b0 + 2 * w + 1) * 2560;
        #pragma unroll
        for (int ks = 0; ks < 4; ++ks) {
            const float4 a0 = *(const float4*)(xa + lc * 128 + 32 * ks + 8 * lg);
            const float4 a1 = *(const float4*)(xa + lc * 128 + 32 * ks + 8 * lg + 4);
            xA0[ks] = (half8){ (h16)a0.x, (h16)a0.y, (h16)a0.z, (h16)a0.w,
                               (h16)a1.x, (h16)a1.y, (h16)a1.z, (h16)a1.w };
            const float4 c0 = *(const float4*)(xb + lc * 128 + 32 * ks + 8 * lg);
            const float4 c1 = *(const float4*)(xb + lc * 128 + 32 * ks + 8 * lg + 4);
            xB0[ks] = (half8){ (h16)c0.x, (h16)c0.y, (h16)c0.z, (h16)c0.w,
                               (h16)c1.x, (h16)c1.y, (h16)c1.z, (h16)c1.w };
        }
        #pragma unroll
        for (int ks = 0; ks < 4; ++ks) {
            half8 va = h8z, vb = h8z;
            if (lc < 4) {
                const float4 a0 = *(const float4*)(xa + (16 + lc) * 128 + 32 * ks + 8 * lg);
                const float4 a1 = *(const float4*)(xa + (16 + lc) * 128 + 32 * ks + 8 * lg + 4);
                va = (half8){ (h16)a0.x, (h16)a0.y, (h16)a0.z, (h16)a0.w,
                              (h16)a1.x, (h16)a1.y, (h16)a1.z, (h16)a1.w };
                const float4 c0 = *(const float4*)(xb + (16 + lc) * 128 + 32 * ks + 8 * lg);
                const float4 c1 = *(const float4*)(xb + (16 + lc) * 128 + 32 * ks + 8 * lg + 4);
                vb = (half8){ (h16)c0.x, (h16)c0.y, (h16)c0.z, (h16)c0.w,
                              (h16)c1.x, (h16)c1.y, (h16)c1.z, (h16)c1.w };
            }
            xA1[ks] = va;
            xB1[ks] = vb;
        }
    }

    // ---- in-register xg = col-max over 20 rows, per batch ----
    // Fold rows 16-19 (lanes lc<4) into the tree via -inf select (0xFC00):
    // max(x,-inf)=x, so lanes lc>=4 contribute only their own row. MFMA
    // operands keep zero-masking; only the max path sees -inf.
    auto xg_store = [&](const half8 (&y0)[4], const half8 (&y1)[4], int row) {
        #pragma unroll
        for (int ks = 0; ks < 4; ++ks) {
            uint4v m0 = __builtin_bit_cast(uint4v, y0[ks]);
            const uint4v m1r = __builtin_bit_cast(uint4v, y1[ks]);
            #pragma unroll
            for (int wd = 0; wd < 4; ++wd) {
                const unsigned m1 = (lc < 4) ? m1r[wd] : 0xFC00FC00u;
                m0[wd] = pkmax(m0[wd], m1);
            }
            #pragma unroll
            for (int s = 1; s < 16; s <<= 1) {
                #pragma unroll
                for (int wd = 0; wd < 4; ++wd)
                    m0[wd] = pkmax(m0[wd], (unsigned)__shfl_xor((int)m0[wd], s));
            }
            if (lc == 0)
                *(half8*)(xgl + swz(row, 32 * ks + 8 * lg)) = __builtin_bit_cast(half8, m0);
        }
    };
    xg_store(xA0, xA1, 2 * w);
    xg_store(xB0, xB1, 2 * w + 1);
    __syncthreads();

    // ---- matvec, 16-row A-tile (r6 pattern, 8 waves): wave w owns ct = w+8i ----
    {
        const half8* fS = (const half8*)(ws + OFF_FRAGS);
        f32x4 sacc[3];
        #pragma unroll
        for (int i = 0; i < 3; ++i) sacc[i] = (f32x4){0.f, 0.f, 0.f, 0.f};
        #pragma unroll
        for (int ks = 0; ks < 4; ++ks) {
            const half8 ag = *(const half8*)(xgl + swz(lc, 32 * ks + 8 * lg));
            #pragma unroll
            for (int i = 0; i < 3; ++i) {
                const int ct = w + 8 * i;
                sacc[i] = MFMA16(ag, fS[(ct * 4 + ks) * 64 + l], sacc[i]);
            }
        }
        // avec/bvec (ct 0..15): C/D row = batch 4lg+r (all 16 valid), col 16(ct&7)+lc
        #pragma unroll
        for (int i = 0; i < 2; ++i) {
            const int ct = w + 8 * i;
            const int v = ct >> 3, c128 = 16 * (ct & 7) + lc;
            const float bias = (v == 0) ? ws[OFF_A0 + c128] : ws[OFF_B0 + c128];
            #pragma unroll
            for (int r = 0; r < 4; ++r)
                avhL[(4 * lg + r) * 256 + v * 128 + c128] = (h16)(sacc[i][r] + bias);
        }
        // c partials (ct = 16+w -> j = 16w+lc)
        {
            const int j = 16 * w + lc;
            const float c1j = ws[OFF_C1 + j];
            #pragma unroll
            for (int r = 0; r < 4; ++r) {
                float v = (sacc[2][r] + c1j) * (float)xgl[swz(4 * lg + r, j)];
                v += __shfl_xor(v, 1); v += __shfl_xor(v, 2);
                v += __shfl_xor(v, 4); v += __shfl_xor(v, 8);
                if (lc == 0) cpart[4 * lg + r][w] = v;
            }
        }
    }
    __syncthreads();
    if (t < 16) {
        float s = ws[OFF_CBASE];
        #pragma unroll
        for (int j = 0; j < 8; ++j) s += cpart[t][j];
        cbs[t] = s;
    }
    __syncthreads();
    // ================= fully independent per-wave from here =================

    const bool hs = (l < 32);
    const int s1 = lc + ((l >> 4) & 1) * 32;   // src for elems 0..3
    const int s2 = s1 + 16;                    // src for elems 4..7
    const half8* fBg = (const half8*)(ws + OFF_FRAGB);

    auto per_batch = [&](const half8 (&y0)[4], const half8 (&y1)[4], const int bi) {
        // s8: col0 = avec, col1 = bvec (from LDS)
        half8 s8[4];
        #pragma unroll
        for (int ks = 0; ks < 4; ++ks) {
            half8 v = h8z;
            if (lc < 2) v = *(const half8*)(avhL + bi * 256 + lc * 128 + 32 * ks + 8 * lg);
            s8[ks] = v;
        }
        // alpha/beta via GEMM
        {
            f32x4 a0c = {0.f, 0.f, 0.f, 0.f}, a1c = {0.f, 0.f, 0.f, 0.f};
            #pragma unroll
            for (int ks = 0; ks < 4; ++ks) {
                a0c = MFMA16(y0[ks], s8[ks], a0c);
                a1c = MFMA16(y1[ks], s8[ks], a1c);
            }
            if (lc == 0) {
                #pragma unroll
                for (int r = 0; r < 4; ++r) abL[bi][4 * lg + r] = a0c[r];
                if (lg == 0) {
                    #pragma unroll
                    for (int r = 0; r < 4; ++r) abL[bi][16 + r] = a1c[r];
                }
            }
            if (lc == 1) {
                #pragma unroll
                for (int r = 0; r < 4; ++r) abL[bi][20 + 4 * lg + r] = a0c[r];
                if (lg == 0) {
                    #pragma unroll
                    for (int r = 0; r < 4; ++r) abL[bi][36 + r] = a1c[r];
                }
            }
        }

        // fused F^T + M^T (r13 machinery; fB rt<4 from LDS, rt>=4 from L1/L2)
        f32x4 macc[2][2];
        #pragma unroll
        for (int mt = 0; mt < 2; ++mt)
            #pragma unroll
            for (int ctn = 0; ctn < 2; ++ctn) macc[mt][ctn] = (f32x4){0.f, 0.f, 0.f, 0.f};
        #pragma unroll
        for (int km = 0; km < 4; ++km) {
            unsigned P[2][2][2];               // [rt-parity][ctn][pk-pair]
            #pragma unroll
            for (int rp = 0; rp < 2; ++rp) {
                const int rt = 2 * km + rp;
                f32x4 f0 = {0.f, 0.f, 0.f, 0.f}, f1 = {0.f, 0.f, 0.f, 0.f};
                #pragma unroll
                for (int ks = 0; ks < 4; ++ks) {
                    const half8 a = (rt < 4)
                        ? *(const half8*)(fBl + ((rt * 4 + ks) * 64 + l) * 8)
                        : fBg[(rt * 4 + ks) * 64 + l];
                    f0 = MFMA16(a, y0[ks], f0);
                    f1 = MFMA16(a, y1[ks], f1);
                }
                P[rp][0][0] = pk2(f0[0], f0[1]); P[rp][0][1] = pk2(f0[2], f0[3]);
                P[rp][1][0] = pk2(f1[0], f1[1]); P[rp][1][1] = pk2(f1[2], f1[3]);
            }
            #pragma unroll
            for (int ctn = 0; ctn < 2; ++ctn) {
                const unsigned A0 = (unsigned)__shfl((int)P[0][ctn][0], s1);
                const unsigned B0 = (unsigned)__shfl((int)P[1][ctn][0], s1);
                const unsigned A1 = (unsigned)__shfl((int)P[0][ctn][1], s1);
                const unsigned B1 = (unsigned)__shfl((int)P[1][ctn][1], s1);
                const unsigned A2 = (unsigned)__shfl((int)P[0][ctn][0], s2);
                const unsigned B2 = (unsigned)__shfl((int)P[1][ctn][0], s2);
                const unsigned A3 = (unsigned)__shfl((int)P[0][ctn][1], s2);
                const unsigned B3 = (unsigned)__shfl((int)P[1][ctn][1], s2);
                const uint4v uu = { hs ? A0 : B0, hs ? A1 : B1,
                                    hs ? A2 : B2, hs ? A3 : B3 };
                const half8 bX = __builtin_bit_cast(half8, uu);
                macc[0][ctn] = MFMA16(y0[km], bX, macc[0][ctn]);
                macc[1][ctn] = MFMA16(y1[km], bX, macc[1][ctn]);
            }
        }
        asm volatile("s_waitcnt lgkmcnt(0)" ::: "memory");   // abL RAW order

        // epilogue (M^T orientation): row m = 16mt+4lg+r, col n = 16ctn+lc
        const float cb = cbs[bi];
        const float an0 = abL[bi][lc];
        const float an1 = (lc < 4) ? abL[bi][16 + lc] : 0.f;
        float bmv0[4], bmv1[4];
        #pragma unroll
        for (int r = 0; r < 4; ++r) {
            bmv0[r] = abL[bi][20 + 4 * lg + r];
            bmv1[r] = (lg == 0) ? abL[bi][36 + r] : 0.f;
        }
        float pv[2][2][4];
        float psum = 0.f;
        #pragma unroll
        for (int mt = 0; mt < 2; ++mt) {
            #pragma unroll
            for (int ctn = 0; ctn < 2; ++ctn) {
                #pragma unroll
                for (int r = 0; r < 4; ++r) {
                    const int n = 16 * ctn + lc;
                    const int m = 16 * mt + 4 * lg + r;
                    const bool valid = (ctn == 0 || lc < 4) && (mt == 0 || lg == 0) && (n != m);
                    const float Mv = (macc[mt][ctn][r] + (ctn ? an1 : an0)
                                      + (mt ? bmv1[r] : bmv0[r]) + cb) * INVS;
                    const float E = __expf(2.f * Mv);
                    const float e = valid ? __expf(-20.f / (E + 1.f)) : 0.f;
                    pv[mt][ctn][r] = e;
                    psum += e;
                }
            }
        }
        #pragma unroll
        for (int off = 32; off > 0; off >>= 1) psum += __shfl_xor(psum, off);
        const float inv = 1.f / psum;

        float* ob = out + (size_t)(b0 + bi) * 400;
        #pragma unroll
        for (int ctn = 0; ctn < 2; ++ctn) {
            if (ctn == 0 || lc < 4) {
                const int n = 16 * ctn + lc;
                #pragma unroll
                for (int mt = 0; mt < 2; ++mt) {
                    if (mt == 0 || lg == 0) {
                        const f32x4 o = { pv[mt][ctn][0] * inv, pv[mt][ctn][1] * inv,
                                          pv[mt][ctn][2] * inv, pv[mt][ctn][3] * inv };
                        *(f32x4*)(ob + n * 20 + 16 * mt + 4 * lg) = o;
                    }
                }
            }
        }
    };

    per_batch(xA0, xA1, 2 * w);
    per_batch(xB0, xB1, 2 * w + 1);
}

extern "C" void kernel_launch(void* const* d_in, const int* in_sizes, int n_in,
                              void* d_out, int out_size, void* d_ws, size_t ws_size,
                              hipStream_t stream) {
    const float* x  = (const float*)d_in[0];
    const float* Wg = (const float*)d_in[1];
    const float* bg = (const float*)d_in[2];
    const float* Wn = (const float*)d_in[3];
    const float* bn = (const float*)d_in[4];
    const float* Wk = (const float*)d_in[5];
    const float* bk = (const float*)d_in[6];
    const float* Wq = (const float*)d_in[7];
    const float* bq = (const float*)d_in[8];
    float* out = (float*)d_out;
    float* ws  = (float*)d_ws;

    k_prep1<<<129, 128, 0, stream>>>(Wk, Wq, bk, bq, bn, bg, ws);
    k_prep2<<<129, 128, 0, stream>>>(Wn, Wg, ws);
    k_prep3<<<129, 128, 0, stream>>>(Wn, Wg, ws);
    k_fused<<<NB / 16, 512, 0, stream>>>(x, ws, out);
}

// Round 16
// 98.495 us; speedup vs baseline: 1.1615x; 1.1615x over previous
//
#include <hip/hip_runtime.h>
#include <hip/hip_bf16.h>
#include <math.h>

// DecoderActor: B=16384, N=20, DM=128.
// M*sqrt(dm) = x B x^T + alpha_n + beta_m + c, B = Wn^T(Wk^T Wq)Wn,
// alpha/beta/c derived from xg = max_n x[n,:].
// Round 16: r14 base (fB fully in LDS, 8 waves x 2 batches) with the xg
// shuffle-reduce (DS pipe, ~224 ops/wave) replaced by a VALU-only DPP
// row_ror rotate-reduce in f32 (-inf fold for rows 16-19). r15's dual-path
// fB reverted (it caused 70MB of scratch spills).
#define DM 128
#define NN 20
#define NB 16384

#define OFF_A      0
#define OFF_AT     16384
#define OFF_WA     32768
#define OFF_WAT    49152
#define OFF_AG     65536
#define OFF_BMAT   81920
#define OFF_S1T    98304
#define OFF_S2T    114688
#define OFF_C2T    131072
#define OFF_U0     147456
#define OFF_V0     147584
#define OFF_T0     147712
#define OFF_W1     147840
#define OFF_AT0    147968
#define OFF_A0     148096
#define OFF_B0     148224
#define OFF_C1     148352
#define OFF_C00    148480
#define OFF_CBASE  148481
// fp16 fragment arrays (packed by prep3; r2/r5/r6/r9-verified layout)
#define OFF_FRAGB  149504            // 16384 h16 : Bmat frags (dual B-op/A-op)
#define OFF_FRAGS  (149504 + 8192)   // 49152 h16 : matvec S frags (16x16x32 B-op)

#define INVS 0.08838834764831845f    // 1/sqrt(128)

typedef _Float16 h16;
typedef h16 half8 __attribute__((ext_vector_type(8)));
typedef h16 half4v __attribute__((ext_vector_type(4)));
typedef h16 half2v __attribute__((ext_vector_type(2)));
typedef float f32x4 __attribute__((ext_vector_type(4)));
typedef unsigned int uint4v __attribute__((ext_vector_type(4)));

#define MFMA16(a, b, c) __builtin_amdgcn_mfma_f32_16x16x32_f16((a), (b), (c), 0, 0, 0)

// r2/r5/r6-verified XOR swizzle (h16 units)
__device__ __forceinline__ int swz(int row, int col) {
    return (row * 128 + col) ^ ((row & 7) << 3);
}

__device__ __forceinline__ unsigned pk2(float a, float b) {
    const half2v p = { (h16)a, (h16)b };
    return __builtin_bit_cast(unsigned, p);
}

// VALU-only 16-lane max reduce step: v_mov_b32_dpp row_ror:N + v_max_f32
template<int CTRL>
__device__ __forceinline__ float dppmaxf(float v) {
    const int r = __builtin_amdgcn_update_dpp(0, __builtin_bit_cast(int, v),
                                              CTRL, 0xF, 0xF, true);
    return fmaxf(v, __builtin_bit_cast(float, r));
}
#define DPPRED(vv) { vv = dppmaxf<0x121>(vv); vv = dppmaxf<0x122>(vv); \
                     vv = dppmaxf<0x124>(vv); vv = dppmaxf<0x128>(vv); }

// fB fragment index for value Bmat[k][j]  (h16 units)
__device__ __forceinline__ int fb_idx(int k, int j) {
    return ((j >> 4) << 11) | ((k >> 5) << 9)
         | ((((k >> 3) & 3) * 16 + (j & 15)) << 3) | (k & 7);
}

// ---------- prep 1: A = Wk^T Wq (and A^T), u0, v0, t0, c00 ----------
__global__ void k_prep1(const float* __restrict__ Wk, const float* __restrict__ Wq,
                        const float* __restrict__ bk, const float* __restrict__ bq,
                        const float* __restrict__ bn, const float* __restrict__ bg,
                        float* __restrict__ ws) {
    const int bx = blockIdx.x, t = threadIdx.x;
    __shared__ float sbuf[128];
    if (bx < 128) {
        sbuf[t] = Wk[t * 128 + bx];
        __syncthreads();
        float a = 0.f;
        #pragma unroll 8
        for (int d = 0; d < 128; ++d) a += sbuf[d] * Wq[d * 128 + t];
        ws[OFF_A  + bx * 128 + t] = a;
        ws[OFF_AT + t * 128 + bx] = a;
    } else {
        float u = 0.f, v = 0.f;
        #pragma unroll 8
        for (int d = 0; d < 128; ++d) {
            u += Wk[d * 128 + t] * bq[d];
            v += Wq[d * 128 + t] * bk[d];
        }
        ws[OFF_U0 + t] = u;
        ws[OFF_V0 + t] = v;
        ws[OFF_T0 + t] = bn[t] + bg[t];
        sbuf[t] = bk[t] * bq[t];
        __syncthreads();
        for (int s = 64; s > 0; s >>= 1) { if (t < s) sbuf[t] += sbuf[t + s]; __syncthreads(); }
        if (t == 0) ws[OFF_C00] = sbuf[0];
    }
}

// ---------- prep 2: WA = Wn^T A, WAT = Wn^T A^T, AG = A Wg; w1, At0, c_base ----------
__global__ void k_prep2(const float* __restrict__ Wn, const float* __restrict__ Wg,
                        float* __restrict__ ws) {
    const int bx = blockIdx.x, t = threadIdx.x;
    __shared__ float s1[128], s2[128];
    if (bx < 128) {
        const int r = bx;
        s1[t] = Wn[t * 128 + r];
        s2[t] = ws[OFF_A + r * 128 + t];
        __syncthreads();
        float wa = 0.f, wat = 0.f, ag = 0.f;
        #pragma unroll 4
        for (int e = 0; e < 128; ++e) {
            wa  += s1[e] * ws[OFF_A  + e * 128 + t];
            wat += s1[e] * ws[OFF_AT + e * 128 + t];
            ag  += s2[e] * Wg[e * 128 + t];
        }
        ws[OFF_WA  + r * 128 + t] = wa;
        ws[OFF_WAT + r * 128 + t] = wat;
        ws[OFF_AG  + r * 128 + t] = ag;
    } else {
        const float t0t = ws[OFF_T0 + t], u0t = ws[OFF_U0 + t], v0t = ws[OFF_V0 + t];
        float w1 = 0.f, at0 = 0.f;
        #pragma unroll 8
        for (int e = 0; e < 128; ++e) {
            const float t0e = ws[OFF_T0 + e];
            w1  += (ws[OFF_A + t * 128 + e] + ws[OFF_AT + t * 128 + e]) * t0e;
            at0 +=  ws[OFF_A + t * 128 + e] * t0e;
        }
        w1 += u0t + v0t;
        ws[OFF_W1  + t] = w1;
        ws[OFF_AT0 + t] = at0;
        s1[t] = t0t * (at0 + u0t + v0t);
        __syncthreads();
        for (int s = 64; s > 0; s >>= 1) { if (t < s) s1[t] += s1[t + s]; __syncthreads(); }
        if (t == 0) ws[OFF_CBASE] = s1[0] + ws[OFF_C00];
    }
}

// ---------- prep 3 (+pack): Bmat/S1/S2/C2 -> fragment scatter; a0, b0, c1 ----------
__global__ void k_prep3(const float* __restrict__ Wn, const float* __restrict__ Wg,
                        float* __restrict__ ws) {
    const int bx = blockIdx.x, t = threadIdx.x;
    __shared__ float wa[128], wat[128], wgc[128];
    h16* fB = (h16*)(ws + OFF_FRAGB);
    h16* fS = (h16*)(ws + OFF_FRAGS);
    if (bx < 128) {
        const int r = bx;
        wa[t]  = ws[OFF_WA  + r * 128 + t];
        wat[t] = ws[OFF_WAT + r * 128 + t];
        wgc[t] = Wg[t * 128 + r];
        __syncthreads();
        float bm = 0.f, s1v = 0.f, s2v = 0.f, c2v = 0.f;
        #pragma unroll 4
        for (int f = 0; f < 128; ++f) {
            bm  += wa[f]  * Wn[f * 128 + t];             // Bmat[r][t]
            s1v += wa[f]  * Wg[f * 128 + t];             // S1[r][t] = Scat[t][r]
            s2v += wat[f] * Wg[f * 128 + t];             // S2[r][t] = Scat[t][r+128]
            c2v += wgc[f] * ws[OFF_AG + f * 128 + t];    // C2[r][t] = Scat[t][r+256]
        }
        fB[fb_idx(r, t)]       = (h16)bm;
        fS[fb_idx(t, r)]       = (h16)s1v;
        fS[fb_idx(t, r + 128)] = (h16)s2v;
        fS[fb_idx(t, r + 256)] = (h16)c2v;
    } else {
        float a0 = 0.f, b0 = 0.f, c1 = 0.f;
        #pragma unroll 8
        for (int f = 0; f < 128; ++f) {
            a0 += ws[OFF_WA  + t * 128 + f] * ws[OFF_T0 + f] + Wn[f * 128 + t] * ws[OFF_U0 + f];
            b0 += ws[OFF_WAT + t * 128 + f] * ws[OFF_T0 + f] + Wn[f * 128 + t] * ws[OFF_V0 + f];
            c1 += Wg[f * 128 + t] * ws[OFF_W1 + f];
        }
        ws[OFF_A0 + t] = a0;
        ws[OFF_B0 + t] = b0;
        ws[OFF_C1 + t] = c1;
    }
}

// ---------- fused main: 8 waves x 2 batches; fB in LDS; x read once ----------
__global__ __launch_bounds__(512, 4) void k_fused(const float* __restrict__ x,
                                                  const float* __restrict__ ws,
                                                  float* __restrict__ out) {
    __shared__ __align__(16) h16 fBl[16384];           // 32 KB: fB table
    __shared__ __align__(16) h16 xgl[16 * 128];        // 4 KB, swizzled
    __shared__ __align__(16) h16 avhL[16 * 2 * 128];   // 8 KB: avec|bvec (bias folded)
    __shared__ float abL[16][40];                      // 2.5 KB
    __shared__ float cpart[16][8];                     // 512 B
    __shared__ float cbs[16];                          // 64 B

    const int t = threadIdx.x, l = t & 63, w = t >> 6;
    const int lc = l & 15, lg = l >> 4;
    const int b0 = blockIdx.x * 16;
    const half8 h8z = {};

    // ---- stage fB table -> LDS (once per block) ----
    {
        const float4* src = (const float4*)(ws + OFF_FRAGB);   // 2048 float4
        float4* dst = (float4*)fBl;
        #pragma unroll
        for (int i = 0; i < 4; ++i) dst[t + 512 * i] = src[t + 512 * i];
    }

    // ---- load x fragments + VALU-DPP xg reduce, per batch ----
    half8 xA0[4], xA1[4], xB0[4], xB1[4];
    const float NI = -INFINITY;
    auto load_batch = [&](const float* xp, half8 (&y0)[4], half8 (&y1)[4], int xgrow) {
        #pragma unroll
        for (int ks = 0; ks < 4; ++ks) {
            const float4 a0 = *(const float4*)(xp + lc * 128 + 32 * ks + 8 * lg);
            const float4 a1 = *(const float4*)(xp + lc * 128 + 32 * ks + 8 * lg + 4);
            y0[ks] = (half8){ (h16)a0.x, (h16)a0.y, (h16)a0.z, (h16)a0.w,
                              (h16)a1.x, (h16)a1.y, (h16)a1.z, (h16)a1.w };
            float4 b0v = {NI, NI, NI, NI}, b1v = {NI, NI, NI, NI};
            half8 va = h8z;
            if (lc < 4) {
                b0v = *(const float4*)(xp + (16 + lc) * 128 + 32 * ks + 8 * lg);
                b1v = *(const float4*)(xp + (16 + lc) * 128 + 32 * ks + 8 * lg + 4);
                va = (half8){ (h16)b0v.x, (h16)b0v.y, (h16)b0v.z, (h16)b0v.w,
                              (h16)b1v.x, (h16)b1v.y, (h16)b1v.z, (h16)b1v.w };
            }
            y1[ks] = va;
            // fold rows 16-19 (-inf on lanes lc>=4), then 16-lane DPP reduce
            float f0 = fmaxf(a0.x, b0v.x), f1 = fmaxf(a0.y, b0v.y);
            float f2 = fmaxf(a0.z, b0v.z), f3 = fmaxf(a0.w, b0v.w);
            float f4 = fmaxf(a1.x, b1v.x), f5 = fmaxf(a1.y, b1v.y);
            float f6 = fmaxf(a1.z, b1v.z), f7 = fmaxf(a1.w, b1v.w);
            DPPRED(f0); DPPRED(f1); DPPRED(f2); DPPRED(f3);
            DPPRED(f4); DPPRED(f5); DPPRED(f6); DPPRED(f7);
            if (lc == 0) {
                *(half8*)(xgl + swz(xgrow, 32 * ks + 8 * lg)) =
                    (half8){ (h16)f0, (h16)f1, (h16)f2, (h16)f3,
                             (h16)f4, (h16)f5, (h16)f6, (h16)f7 };
            }
        }
    };
    load_batch(x + (size_t)(b0 + 2 * w) * 2560,     xA0, xA1, 2 * w);
    load_batch(x + (size_t)(b0 + 2 * w + 1) * 2560, xB0, xB1, 2 * w + 1);
    __syncthreads();

    // ---- matvec, 16-row A-tile (r6 pattern, 8 waves): wave w owns ct = w+8i ----
    {
        const half8* fS = (const half8*)(ws + OFF_FRAGS);
        f32x4 sacc[3];
        #pragma unroll
        for (int i = 0; i < 3; ++i) sacc[i] = (f32x4){0.f, 0.f, 0.f, 0.f};
        #pragma unroll
        for (int ks = 0; ks < 4; ++ks) {
            const half8 ag = *(const half8*)(xgl + swz(lc, 32 * ks + 8 * lg));
            #pragma unroll
            for (int i = 0; i < 3; ++i) {
                const int ct = w + 8 * i;
                sacc[i] = MFMA16(ag, fS[(ct * 4 + ks) * 64 + l], sacc[i]);
            }
        }
        // avec/bvec (ct 0..15): C/D row = batch 4lg+r (all 16 valid), col 16(ct&7)+lc
        #pragma unroll
        for (int i = 0; i < 2; ++i) {
            const int ct = w + 8 * i;
            const int v = ct >> 3, c128 = 16 * (ct & 7) + lc;
            const float bias = (v == 0) ? ws[OFF_A0 + c128] : ws[OFF_B0 + c128];
            #pragma unroll
            for (int r = 0; r < 4; ++r)
                avhL[(4 * lg + r) * 256 + v * 128 + c128] = (h16)(sacc[i][r] + bias);
        }
        // c partials (ct = 16+w -> j = 16w+lc)
        {
            const int j = 16 * w + lc;
            const float c1j = ws[OFF_C1 + j];
            #pragma unroll
            for (int r = 0; r < 4; ++r) {
                float v = (sacc[2][r] + c1j) * (float)xgl[swz(4 * lg + r, j)];
                v += __shfl_xor(v, 1); v += __shfl_xor(v, 2);
                v += __shfl_xor(v, 4); v += __shfl_xor(v, 8);
                if (lc == 0) cpart[4 * lg + r][w] = v;
            }
        }
    }
    __syncthreads();
    if (t < 16) {
        float s = ws[OFF_CBASE];
        #pragma unroll
        for (int j = 0; j < 8; ++j) s += cpart[t][j];
        cbs[t] = s;
    }
    __syncthreads();
    // ================= fully independent per-wave from here =================

    const bool hs = (l < 32);
    const int s1 = lc + ((l >> 4) & 1) * 32;   // src for elems 0..3
    const int s2 = s1 + 16;                    // src for elems 4..7

    auto per_batch = [&](const half8 (&y0)[4], const half8 (&y1)[4], const int bi) {
        // s8: col0 = avec, col1 = bvec (from LDS)
        half8 s8[4];
        #pragma unroll
        for (int ks = 0; ks < 4; ++ks) {
            half8 v = h8z;
            if (lc < 2) v = *(const half8*)(avhL + bi * 256 + lc * 128 + 32 * ks + 8 * lg);
            s8[ks] = v;
        }
        // alpha/beta via GEMM
        {
            f32x4 a0c = {0.f, 0.f, 0.f, 0.f}, a1c = {0.f, 0.f, 0.f, 0.f};
            #pragma unroll
            for (int ks = 0; ks < 4; ++ks) {
                a0c = MFMA16(y0[ks], s8[ks], a0c);
                a1c = MFMA16(y1[ks], s8[ks], a1c);
            }
            if (lc == 0) {
                #pragma unroll
                for (int r = 0; r < 4; ++r) abL[bi][4 * lg + r] = a0c[r];
                if (lg == 0) {
                    #pragma unroll
                    for (int r = 0; r < 4; ++r) abL[bi][16 + r] = a1c[r];
                }
            }
            if (lc == 1) {
                #pragma unroll
                for (int r = 0; r < 4; ++r) abL[bi][20 + 4 * lg + r] = a0c[r];
                if (lg == 0) {
                    #pragma unroll
                    for (int r = 0; r < 4; ++r) abL[bi][36 + r] = a1c[r];
                }
            }
        }

        // fused F^T + M^T (fB from LDS)
        f32x4 macc[2][2];
        #pragma unroll
        for (int mt = 0; mt < 2; ++mt)
            #pragma unroll
            for (int ctn = 0; ctn < 2; ++ctn) macc[mt][ctn] = (f32x4){0.f, 0.f, 0.f, 0.f};
        #pragma unroll
        for (int km = 0; km < 4; ++km) {
            unsigned P[2][2][2];               // [rt-parity][ctn][pk-pair]
            #pragma unroll
            for (int rp = 0; rp < 2; ++rp) {
                const int rt = 2 * km + rp;
                f32x4 f0 = {0.f, 0.f, 0.f, 0.f}, f1 = {0.f, 0.f, 0.f, 0.f};
                #pragma unroll
                for (int ks = 0; ks < 4; ++ks) {
                    const half8 a = *(const half8*)(fBl + ((rt * 4 + ks) * 64 + l) * 8);
                    f0 = MFMA16(a, y0[ks], f0);
                    f1 = MFMA16(a, y1[ks], f1);
                }
                P[rp][0][0] = pk2(f0[0], f0[1]); P[rp][0][1] = pk2(f0[2], f0[3]);
                P[rp][1][0] = pk2(f1[0], f1[1]); P[rp][1][1] = pk2(f1[2], f1[3]);
            }
            #pragma unroll
            for (int ctn = 0; ctn < 2; ++ctn) {
                const unsigned A0 = (unsigned)__shfl((int)P[0][ctn][0], s1);
                const unsigned B0 = (unsigned)__shfl((int)P[1][ctn][0], s1);
                const unsigned A1 = (unsigned)__shfl((int)P[0][ctn][1], s1);
                const unsigned B1 = (unsigned)__shfl((int)P[1][ctn][1], s1);
                const unsigned A2 = (unsigned)__shfl((int)P[0][ctn][0], s2);
                const unsigned B2 = (unsigned)__shfl((int)P[1][ctn][0], s2);
                const unsigned A3 = (unsigned)__shfl((int)P[0][ctn][1], s2);
                const unsigned B3 = (unsigned)__shfl((int)P[1][ctn][1], s2);
                const uint4v uu = { hs ? A0 : B0, hs ? A1 : B1,
                                    hs ? A2 : B2, hs ? A3 : B3 };
                const half8 bX = __builtin_bit_cast(half8, uu);
                macc[0][ctn] = MFMA16(y0[km], bX, macc[0][ctn]);
                macc[1][ctn] = MFMA16(y1[km], bX, macc[1][ctn]);
            }
        }
        asm volatile("s_waitcnt lgkmcnt(0)" ::: "memory");   // abL RAW order

        // epilogue (M^T orientation): row m = 16mt+4lg+r, col n = 16ctn+lc
        const float cb = cbs[bi];
        const float an0 = abL[bi][lc];
        const float an1 = (lc < 4) ? abL[bi][16 + lc] : 0.f;
        float bmv0[4], bmv1[4];
        #pragma unroll
        for (int r = 0; r < 4; ++r) {
            bmv0[r] = abL[bi][20 + 4 * lg + r];
            bmv1[r] = (lg == 0) ? abL[bi][36 + r] : 0.f;
        }
        float pv[2][2][4];
        float psum = 0.f;
        #pragma unroll
        for (int mt = 0; mt < 2; ++mt) {
            #pragma unroll
            for (int ctn = 0; ctn < 2; ++ctn) {
                #pragma unroll
                for (int r = 0; r < 4; ++r) {
                    const int n = 16 * ctn + lc;
                    const int m = 16 * mt + 4 * lg + r;
                    const bool valid = (ctn == 0 || lc < 4) && (mt == 0 || lg == 0) && (n != m);
                    const float Mv = (macc[mt][ctn][r] + (ctn ? an1 : an0)
                                      + (mt ? bmv1[r] : bmv0[r]) + cb) * INVS;
                    const float E = __expf(2.f * Mv);
                    const float e = valid ? __expf(-20.f / (E + 1.f)) : 0.f;
                    pv[mt][ctn][r] = e;
                    psum += e;
                }
            }
        }
        #pragma unroll
        for (int off = 32; off > 0; off >>= 1) psum += __shfl_xor(psum, off);
        const float inv = 1.f / psum;

        float* ob = out + (size_t)(b0 + bi) * 400;
        #pragma unroll
        for (int ctn = 0; ctn < 2; ++ctn) {
            if (ctn == 0 || lc < 4) {
                const int n = 16 * ctn + lc;
                #pragma unroll
                for (int mt = 0; mt < 2; ++mt) {
                    if (mt == 0 || lg == 0) {
                        const f32x4 o = { pv[mt][ctn][0] * inv, pv[mt][ctn][1] * inv,
                                          pv[mt][ctn][2] * inv, pv[mt][ctn][3] * inv };
                        *(f32x4*)(ob + n * 20 + 16 * mt + 4 * lg) = o;
                    }
                }
            }
        }
    };

    per_batch(xA0, xA1, 2 * w);
    per_batch(xB0, xB1, 2 * w + 1);
}

extern "C" void kernel_launch(void* const* d_in, const int* in_sizes, int n_in,
                              void* d_out, int out_size, void* d_ws, size_t ws_size,
                              hipStream_t stream) {
    const float* x  = (const float*)d_in[0];
    const float* Wg = (const float*)d_in[1];
    const float* bg = (const float*)d_in[2];
    const float* Wn = (const float*)d_in[3];
    const float* bn = (const float*)d_in[4];
    const float* Wk = (const float*)d_in[5];
    const float* bk = (const float*)d_in[6];
    const float* Wq = (const float*)d_in[7];
    const float* bq = (const float*)d_in[8];
    float* out = (float*)d_out;
    float* ws  = (float*)d_ws;

    k_prep1<<<129, 128, 0, stream>>>(Wk, Wq, bk, bq, bn, bg, ws);
    k_prep2<<<129, 128, 0, stream>>>(Wn, Wg, ws);
    k_prep3<<<129, 128, 0, stream>>>(Wn, Wg, ws);
    k_fused<<<NB / 16, 512, 0, stream>>>(x, ws, out);
}